// Round 3
// baseline (251.515 us; speedup 1.0000x reference)
//
#include <hip/hip_runtime.h>
#include <hip/hip_bf16.h>

#define NBH 64
#define NSEQ 2048
#define DD 128
#define EPS 1e-6f

typedef __bf16 bf16x8 __attribute__((ext_vector_type(8)));
typedef __bf16 bf16x4 __attribute__((ext_vector_type(4)));
typedef float  f32x4  __attribute__((ext_vector_type(4)));

__device__ __forceinline__ float elu1(float x) {
    // elu(x)+1 = x+1 (x>0), exp(x) (x<=0)
    return x > 0.f ? x + 1.f : __expf(x);
}

// XOR swizzle for [128][64] bf16 tiles (16B slots): element index for row r,
// k-offset k0 (multiple of 8).  Writes (column pattern d=4c+i) and MFMA row
// reads both land 8 lanes per 4-bank group = wave64 b128 floor.
__device__ __forceinline__ int ldsidx64(int r, int k0) {
    int sw = ((((r >> 2) & 7) ^ ((r & 1) << 2)) << 3);
    return r * 64 + (sw ^ k0);
}

// ---------------------------------------------------------------------------
// Phase 1: partial KV^T.  grid (8, 64) = (256-row chunk, bh), 512 threads.
// part[(bh*8+s)][e][d] = sum over chunk rows n of Vf[n,e]*Kf[n,d]   (fp32)
// Single 32KB LDS buffer pair + mloc => 3 blocks/CU (launch_bounds 512,6
// caps VGPR at 85; 24 waves/CU).  Rotated schedule: tile t+1 loads issue
// before tile-t MFMA.  Waves in 2x4 grid (64e x 32d patches): LDS broadcast
// reads cut 33% vs 1x8.
// ---------------------------------------------------------------------------
__global__ __launch_bounds__(512, 6) void kv_partial_kernel(
    const float* __restrict__ K, const float* __restrict__ V,
    const float* __restrict__ mask, float* __restrict__ part)
{
    __shared__ __bf16 KfT[128 * 64];   // [d][n]  16 KB
    __shared__ __bf16 VfT[128 * 64];   // [e][n]  16 KB
    __shared__ float  mloc[256];

    const int s    = blockIdx.x;
    const int bh   = blockIdx.y;
    const int b    = bh >> 4;
    const int t    = threadIdx.x;
    const int lane = t & 63;
    const int w    = t >> 6;       // wave 0..7
    const int quad = lane >> 4;
    const int col  = lane & 15;
    const int n0   = s * 256;
    const int we   = w >> 2;       // 0..1: e-base we*64
    const int wd   = w & 3;        // 0..3: d-base wd*32

    // staging role: K-half / V-half (wave-uniform)
    const int isV = t >> 8;
    const int c   = t & 31;        // d-group: d = 4c+i
    const int rg  = (t >> 5) & 7;  // rows rg*8 .. +7 within 64-row tile

    const f32x4* S4 = (const f32x4*)((isV ? V : K) + ((size_t)bh * NSEQ + n0) * DD);
    __bf16* myT = isV ? VfT : KfT;

    f32x4 acc[8];   // acc[at*2+bt]: e = we*64+at*16+quad*4+r, d = wd*32+bt*16+col
    #pragma unroll
    for (int i = 0; i < 8; ++i) acc[i] = (f32x4){0.f, 0.f, 0.f, 0.f};

    f32x4 xr[8];    // staging registers (32 VGPR)

    auto load_tile = [&](int tile) {
        #pragma unroll
        for (int j = 0; j < 8; ++j)
            xr[j] = S4[(tile * 64 + rg * 8 + j) * 32 + c];
    };

    auto stage = [&](int tile) {
        float ml[8];
        #pragma unroll
        for (int j = 0; j < 8; ++j) ml[j] = mloc[tile * 64 + rg * 8 + j];
        #pragma unroll
        for (int i = 0; i < 4; ++i) {
            bf16x8 xc;
            if (!isV) {
                #pragma unroll
                for (int j = 0; j < 8; ++j) xc[j] = (__bf16)(elu1(xr[j][i]) * ml[j]);
            } else {
                #pragma unroll
                for (int j = 0; j < 8; ++j) xc[j] = (__bf16)(xr[j][i] * ml[j]);
            }
            int d = 4 * c + i;
            *(bf16x8*)&myT[ldsidx64(d, rg << 3)] = xc;
        }
    };

    auto mfma_tile = [&]() {
        #pragma unroll
        for (int kk = 0; kk < 2; ++kk) {
            int k0 = kk * 32 + quad * 8;
            bf16x8 b0 = *(bf16x8*)&KfT[ldsidx64(wd * 32 + col, k0)];
            bf16x8 b1 = *(bf16x8*)&KfT[ldsidx64(wd * 32 + 16 + col, k0)];
            #pragma unroll
            for (int at = 0; at < 4; ++at) {
                bf16x8 aa = *(bf16x8*)&VfT[ldsidx64(we * 64 + at * 16 + col, k0)];
                acc[at * 2]     = __builtin_amdgcn_mfma_f32_16x16x32_bf16(aa, b0, acc[at * 2], 0, 0, 0);
                acc[at * 2 + 1] = __builtin_amdgcn_mfma_f32_16x16x32_bf16(aa, b1, acc[at * 2 + 1], 0, 0, 0);
            }
        }
    };

    if (t < 256) mloc[t] = mask[b * NSEQ + n0 + t];
    load_tile(0);
    __syncthreads();                 // mloc visible
    stage(0);
    __syncthreads();                 // tile 0 staged

    load_tile(1); mfma_tile(); __syncthreads(); stage(1); __syncthreads();
    load_tile(2); mfma_tile(); __syncthreads(); stage(2); __syncthreads();
    load_tile(3); mfma_tile(); __syncthreads(); stage(3); __syncthreads();
    mfma_tile();

    // store partial KV^T (fp32), layout [e][d]
    float* po = part + (((size_t)bh * 8 + s) << 14);
    #pragma unroll
    for (int at = 0; at < 4; ++at) {
        #pragma unroll
        for (int r = 0; r < 4; ++r) {
            int e = we * 64 + at * 16 + quad * 4 + r;
            po[e * 128 + wd * 32 + col]      = acc[at * 2][r];
            po[e * 128 + wd * 32 + 16 + col] = acc[at * 2 + 1][r];
        }
    }
}

// ---------------------------------------------------------------------------
// Phase 2: sum 8 partials -> bf16 KVT[bh][e][d].  262144 threads, 4 elems ea.
// ---------------------------------------------------------------------------
__global__ __launch_bounds__(256) void kv_reduce_kernel(
    const float* __restrict__ part, __bf16* __restrict__ kvt)
{
    int gid = blockIdx.x * 256 + threadIdx.x;   // 0..262143
    int i   = gid * 4;
    int bh  = i >> 14;
    int ii  = i & 16383;
    const float* p = part + (((size_t)bh * 8) << 14) + ii;
    f32x4 sum = (f32x4){0.f, 0.f, 0.f, 0.f};
    #pragma unroll
    for (int s = 0; s < 8; ++s)
        sum += *(const f32x4*)(p + ((size_t)s << 14));
    bf16x4 o;
    o[0] = (__bf16)sum[0]; o[1] = (__bf16)sum[1];
    o[2] = (__bf16)sum[2]; o[3] = (__bf16)sum[3];
    *(bf16x4*)&kvt[i] = o;
}

// ---------------------------------------------------------------------------
// Phase 3: out = rmsnorm( Qf @ KV ).  grid (16, 64) = (128-row chunk, bh),
// 256 threads.  KVT staged ONCE per block, two 64-row Q-chunks computed from
// it; chunk-1 Q loads issued before chunk-0 compute (latency hidden).
// Q goes straight from global to MFMA A-fragments (no Q LDS, one barrier).
// ---------------------------------------------------------------------------
__global__ __launch_bounds__(256, 4) void qkv_norm_kernel(
    const float* __restrict__ Q, const __bf16* __restrict__ kvt,
    float* __restrict__ out)
{
    __shared__ __bf16 KVT[128 * 136];

    const int bh   = blockIdx.y;
    const int row0 = blockIdx.x * 128;
    const int t    = threadIdx.x;
    const int lane = t & 63;
    const int w    = t >> 6;     // wave 0..3 -> rows [w*16, +16) of each chunk
    const int quad = lane >> 4;
    const int col  = lane & 15;

    const int qrow = w * 16 + col;
    const f32x4* q4 = (const f32x4*)(Q + ((size_t)bh * NSEQ + row0 + qrow) * DD);

    // issue chunk-0 Q loads first (HBM, longest latency)
    f32x4 qr0[8];
    #pragma unroll
    for (int kk = 0; kk < 4; ++kk) {
        qr0[2 * kk]     = q4[kk * 8 + quad * 2];
        qr0[2 * kk + 1] = q4[kk * 8 + quad * 2 + 1];
    }

    // stage KVT (bf16, 128x128) into padded LDS (stride 136: bank floor for
    // both the staging writes and the MFMA b128 reads)
    {
        const __bf16* src = kvt + ((size_t)bh << 14);
        #pragma unroll
        for (int i = 0; i < 8; ++i) {
            int idx = i * 256 + t;
            int e   = idx >> 4;
            int dd  = (idx & 15) * 8;
            *(bf16x8*)&KVT[e * 136 + dd] = *(const bf16x8*)&src[e * 128 + dd];
        }
    }
    __syncthreads();

    // convert chunk-0 A fragments (waits on qr0; KVT staging already done)
    bf16x8 a[4];
    #pragma unroll
    for (int kk = 0; kk < 4; ++kk) {
        #pragma unroll
        for (int h = 0; h < 2; ++h) {
            f32x4 q = qr0[2 * kk + h];
            #pragma unroll
            for (int u = 0; u < 4; ++u)
                a[kk][h * 4 + u] = (__bf16)elu1(q[u]);
        }
    }

    // issue chunk-1 Q loads (rows +64) — in flight across chunk-0 compute
    f32x4 qr1[8];
    #pragma unroll
    for (int kk = 0; kk < 4; ++kk) {
        qr1[2 * kk]     = q4[2048 + kk * 8 + quad * 2];
        qr1[2 * kk + 1] = q4[2048 + kk * 8 + quad * 2 + 1];
    }

    float* ob = out + ((size_t)bh * NSEQ + row0) * DD;

    #pragma unroll
    for (int chunk = 0; chunk < 2; ++chunk) {
        f32x4 acc[8];
        #pragma unroll
        for (int et = 0; et < 8; ++et) acc[et] = (f32x4){0.f, 0.f, 0.f, 0.f};

        #pragma unroll
        for (int kk = 0; kk < 4; ++kk) {
            int k0 = kk * 32 + quad * 8;
            #pragma unroll
            for (int et = 0; et < 8; ++et) {
                bf16x8 bb = *(bf16x8*)&KVT[(et * 16 + col) * 136 + k0];
                acc[et] = __builtin_amdgcn_mfma_f32_16x16x32_bf16(a[kk], bb, acc[et], 0, 0, 0);
            }
        }

        // RMS norm per row + store.  C layout: row = quad*4+reg, col = lane&15.
        #pragma unroll
        for (int r = 0; r < 4; ++r) {
            float p = 0.f;
            #pragma unroll
            for (int et = 0; et < 8; ++et) p += acc[et][r] * acc[et][r];
            p += __shfl_xor(p, 1);
            p += __shfl_xor(p, 2);
            p += __shfl_xor(p, 4);
            p += __shfl_xor(p, 8);   // sum over the 16 lanes holding this row
            float scale = rsqrtf(p * (1.0f / 128.0f) + EPS);
            int orow = chunk * 64 + w * 16 + quad * 4 + r;
            #pragma unroll
            for (int et = 0; et < 8; ++et)
                ob[orow * DD + et * 16 + col] = acc[et][r] * scale;
        }

        // convert chunk-1 A fragments for next pass (qr1 landed during chunk 0)
        if (chunk == 0) {
            #pragma unroll
            for (int kk = 0; kk < 4; ++kk) {
                #pragma unroll
                for (int h = 0; h < 2; ++h) {
                    f32x4 q = qr1[2 * kk + h];
                    #pragma unroll
                    for (int u = 0; u < 4; ++u)
                        a[kk][h * 4 + u] = (__bf16)elu1(q[u]);
                }
            }
        }
    }
}

extern "C" void kernel_launch(void* const* d_in, const int* in_sizes, int n_in,
                              void* d_out, int out_size, void* d_ws, size_t ws_size,
                              hipStream_t stream) {
    const float* Q    = (const float*)d_in[0];
    const float* K    = (const float*)d_in[1];
    const float* V    = (const float*)d_in[2];
    const float* mask = (const float*)d_in[3];
    float* out = (float*)d_out;

    float*  part = (float*)d_ws;                                   // 32 MB
    __bf16* kvt  = (__bf16*)((char*)d_ws + (size_t)NBH * 8 * 16384 * 4);

    kv_partial_kernel<<<dim3(8, NBH), 512, 0, stream>>>(K, V, mask, part);
    kv_reduce_kernel<<<1024, 256, 0, stream>>>(part, kvt);
    qkv_norm_kernel<<<dim3(16, NBH), 256, 0, stream>>>(Q, kvt, out);
}